// Round 1
// baseline (1019.710 us; speedup 1.0000x reference)
//
#include <hip/hip_runtime.h>
#include <hip/hip_bf16.h>

#define WF_LEN 9198
#define BATCH  16384
#define NKS_TOTAL 288   /* ceil(9198/32) = 288 K-steps of 32 (padded to 9216) */
#define KSPLIT 2
#define NKS_HALF 144
#define NCOL 256

typedef unsigned short u16;
typedef __attribute__((ext_vector_type(8))) short bf16x8;   // 8 bf16 (4 VGPRs)
typedef __attribute__((ext_vector_type(4))) float f32x4;    // 4 fp32 acc

static __device__ __forceinline__ u16 f2bf(float f) {
    union { float f; unsigned u; } v; v.f = f;
    unsigned u = v.u;
    return (u16)((u + 0x7fffu + ((u >> 16) & 1u)) >> 16);   // RNE
}

// ---------------------------------------------------------------------------
// Kernel 1: build Wbig [9216 x 256] bf16, pre-swizzled into MFMA B-fragment
// order. Column c = layer*32 + net*16 + h.  B-frag layout for 16x16x32:
// lane l holds B[k = (l>>4)*8 + j][n = (l&15)], j=0..7.
// Memory order: frag[(ksg*16 + nt)*64 + lane][j]  (16 B per lane, contiguous 1 KB/frag)
// ---------------------------------------------------------------------------
__global__ __launch_bounds__(256) void prep_b(const float* __restrict__ sW1,
                                              const float* __restrict__ tW1,
                                              u16* __restrict__ bfrag) {
    const int ksg  = blockIdx.x;                 // 0..287
    const int t    = threadIdx.x;
    const int nt   = blockIdx.y * 4 + (t >> 6);  // 0..15
    const int lane = t & 63;
    const int q    = lane >> 4;
    const int ln   = lane & 15;
    const int c    = nt * 16 + ln;               // col 0..255
    const int layer = c >> 5;
    const int net   = (c >> 4) & 1;
    const int h     = c & 15;
    const float* W = (net ? tW1 : sW1) + (size_t)layer * (9202 * 16) + h;
    const int kb = ksg * 32 + q * 8;
    u16 vals[8];
#pragma unroll
    for (int j = 0; j < 8; ++j) {
        int k = kb + j;
        float v = (k < WF_LEN) ? W[(size_t)(4 + k) * 16] : 0.f;
        vals[j] = f2bf(v);
    }
    u16* dst = bfrag + ((size_t)(ksg * 16 + nt) * 64 + lane) * 8;
    *(uint4*)dst = *(const uint4*)vals;
}

// ---------------------------------------------------------------------------
// Kernel 2: precomp[ky][row][c] partial = waveform[row, khalf] @ Wbig[khalf, c]
// Block: 256 thr (4 waves), tile 64 rows x 256 cols, BK=32, K split in 2.
// A: fp32 global -> cvt bf16 -> LDS (pad 40 halves/row), double-buffered.
// B: direct global->VGPR from pre-fragmented buffer (L2-resident).
// ---------------------------------------------------------------------------
__device__ __forceinline__ void load_a8(const float* aptr, int kb, int akoff, float v[8]) {
    if (kb + 32 <= WF_LEN) {
        float2 q0 = *(const float2*)(aptr + kb);
        float2 q1 = *(const float2*)(aptr + kb + 2);
        float2 q2 = *(const float2*)(aptr + kb + 4);
        float2 q3 = *(const float2*)(aptr + kb + 6);
        v[0]=q0.x; v[1]=q0.y; v[2]=q1.x; v[3]=q1.y;
        v[4]=q2.x; v[5]=q2.y; v[6]=q3.x; v[7]=q3.y;
    } else {
#pragma unroll
        for (int e = 0; e < 8; ++e)
            v[e] = (kb + akoff + e < WF_LEN) ? aptr[kb + e] : 0.f;
    }
}

__device__ __forceinline__ void store_a8(u16* dst, const float v[8]) {
    u16 u[8];
#pragma unroll
    for (int e = 0; e < 8; ++e) u[e] = f2bf(v[e]);
    *(uint4*)dst = *(const uint4*)u;
}

__global__ __launch_bounds__(256) void gemm_big(const float* __restrict__ wf,
                                                const u16* __restrict__ bfrag,
                                                float* __restrict__ precomp) {
    __shared__ u16 As[2][64 * 40];      // 64 rows x 32 k, pad to 40 halves (80 B) / row

    const int t    = threadIdx.x;
    const int wave = t >> 6;
    const int lane = t & 63;
    const int r0   = blockIdx.x * 64;
    const int ky   = blockIdx.y;
    const int ks_base = ky * NKS_HALF;

    // A staging: thread t handles row t>>2, k-chunk (t&3)*8
    const int arow  = t >> 2;
    const int akoff = (t & 3) * 8;
    const float* aptr = wf + (size_t)(r0 + arow) * WF_LEN + akoff;
    const int awr_idx = arow * 40 + akoff;

    // A-frag read coords: lane l -> A[m = l&15][k = (l>>4)*8 + j]
    const int frow = lane & 15;
    const int fq   = lane >> 4;

    // B-frag base for this wave (covers n-tiles wave*4 .. wave*4+3)
    const u16* bptr = bfrag + ((size_t)(ks_base * 16 + wave * 4) * 64 + lane) * 8;

    f32x4 acc[4][4];
#pragma unroll
    for (int a = 0; a < 4; ++a)
#pragma unroll
        for (int b = 0; b < 4; ++b)
            acc[a][b] = (f32x4){0.f, 0.f, 0.f, 0.f};

    // prologue: stage K-step 0
    {
        float a0[8];
        load_a8(aptr, ks_base * 32, akoff, a0);
        store_a8(&As[0][awr_idx], a0);
    }
    __syncthreads();

    for (int ks = 0; ks < NKS_HALF; ++ks) {
        const int buf = ks & 1;

        // B fragments first (L2, short latency)
        bf16x8 bfr[4];
#pragma unroll
        for (int j = 0; j < 4; ++j)
            bfr[j] = *(const bf16x8*)(bptr + (size_t)ks * 8192 + j * 512);

        // prefetch next A tile (HBM, long latency) into regs
        float a_nxt[8];
        const bool have_next = (ks + 1 < NKS_HALF);
        if (have_next)
            load_a8(aptr, (ks_base + ks + 1) * 32, akoff, a_nxt);

        // A fragments from LDS
        bf16x8 afr[4];
#pragma unroll
        for (int mt = 0; mt < 4; ++mt)
            afr[mt] = *(const bf16x8*)&As[buf][(mt * 16 + frow) * 40 + fq * 8];

#pragma unroll
        for (int mt = 0; mt < 4; ++mt)
#pragma unroll
            for (int j = 0; j < 4; ++j)
                acc[mt][j] = __builtin_amdgcn_mfma_f32_16x16x32_bf16(
                    afr[mt], bfr[j], acc[mt][j], 0, 0, 0);

        if (have_next)
            store_a8(&As[buf ^ 1][awr_idx], a_nxt);
        __syncthreads();
    }

    // epilogue: C/D layout col = lane&15, row = (lane>>4)*4 + reg
    float* outp = precomp + (size_t)ky * ((size_t)BATCH * NCOL);
    const int ccol  = lane & 15;
    const int crow4 = (lane >> 4) * 4;
#pragma unroll
    for (int mt = 0; mt < 4; ++mt) {
#pragma unroll
        for (int j = 0; j < 4; ++j) {
            const int col  = wave * 64 + j * 16 + ccol;
            const int rowb = r0 + mt * 16 + crow4;
#pragma unroll
            for (int i = 0; i < 4; ++i)
                outp[(size_t)(rowb + i) * NCOL + col] = acc[mt][j][i];
        }
    }
}

// ---------------------------------------------------------------------------
// Kernel 3: sequential 8-layer recurrence, one thread per batch row.
// precomp layout [row][layer][net][h] -> one 128 B line per (row,layer).
// Small weights read at wave-uniform addresses -> scalar loads.
// ---------------------------------------------------------------------------
__device__ __forceinline__ float leaky(float v) { return v >= 0.f ? v : 0.01f * v; }

__device__ __forceinline__ void mlp4(const float* __restrict__ p0,
                                     const float* __restrict__ p1,
                                     const float zm[4],
                                     const float* __restrict__ W1,
                                     const float* __restrict__ b1,
                                     const float* __restrict__ W2,
                                     const float* __restrict__ b2,
                                     const float* __restrict__ W3,
                                     const float* __restrict__ b3,
                                     float o[4]) {
    float pv[16];
    {
        const float4* A = (const float4*)p0;
        const float4* B = (const float4*)p1;
#pragma unroll
        for (int g = 0; g < 4; ++g) {
            float4 a = A[g], b = B[g];
            pv[g*4+0] = a.x + b.x; pv[g*4+1] = a.y + b.y;
            pv[g*4+2] = a.z + b.z; pv[g*4+3] = a.w + b.w;
        }
    }
    float h1[16];
#pragma unroll
    for (int h = 0; h < 16; ++h) {
        float v = pv[h] + b1[h];
#pragma unroll
        for (int d = 0; d < 4; ++d) v += zm[d] * W1[d * 16 + h];
        h1[h] = leaky(v);
    }
    float h2[16];
#pragma unroll
    for (int ho = 0; ho < 16; ++ho) {
        float v = b2[ho];
#pragma unroll
        for (int hi = 0; hi < 16; ++hi) v += h1[hi] * W2[hi * 16 + ho];
        h2[ho] = leaky(v);
    }
#pragma unroll
    for (int d = 0; d < 4; ++d) {
        float v = b3[d];
#pragma unroll
        for (int h = 0; h < 16; ++h) v += h2[h] * W3[h * 4 + d];
        o[d] = v;
    }
}

__global__ __launch_bounds__(64) void tail_kernel(
    const float* __restrict__ x, const float* __restrict__ mask,
    const float* __restrict__ sW1, const float* __restrict__ sW2, const float* __restrict__ sW3,
    const float* __restrict__ sb1, const float* __restrict__ sb2, const float* __restrict__ sb3,
    const float* __restrict__ tW1, const float* __restrict__ tW2, const float* __restrict__ tW3,
    const float* __restrict__ tb1, const float* __restrict__ tb2, const float* __restrict__ tb3,
    const float* __restrict__ precomp, float* __restrict__ out) {
    const int row = blockIdx.x * blockDim.x + threadIdx.x;
    const float* p0 = precomp + (size_t)row * NCOL;
    const float* p1 = precomp + (size_t)BATCH * NCOL + (size_t)row * NCOL;

    float z[4];
    { float4 v = *(const float4*)(x + (size_t)row * 4); z[0]=v.x; z[1]=v.y; z[2]=v.z; z[3]=v.w; }
    float ld = 0.f;

    for (int i = 7; i >= 0; --i) {
        float m[4], zm[4];
#pragma unroll
        for (int d = 0; d < 4; ++d) { m[d] = mask[i * 4 + d]; zm[d] = m[d] * z[d]; }

        float so[4], to_[4];
        mlp4(p0 + i * 32,      p1 + i * 32,      zm,
             sW1 + (size_t)i * 9202 * 16, sb1 + i * 16,
             sW2 + i * 256, sb2 + i * 16, sW3 + i * 64, sb3 + i * 4, so);
        mlp4(p0 + i * 32 + 16, p1 + i * 32 + 16, zm,
             tW1 + (size_t)i * 9202 * 16, tb1 + i * 16,
             tW2 + i * 256, tb2 + i * 16, tW3 + i * 64, tb3 + i * 4, to_);

#pragma unroll
        for (int d = 0; d < 4; ++d) {
            float om = 1.f - m[d];
            float s  = tanhf(so[d]) * om;
            float tt = to_[d] * om;
            z[d] = om * (z[d] - tt) * expf(-s) + zm[d];
            ld -= s;
        }
    }

    float4 zv; zv.x = z[0]; zv.y = z[1]; zv.z = z[2]; zv.w = z[3];
    *(float4*)(out + (size_t)row * 4) = zv;
    out[(size_t)BATCH * 4 + row] = ld;
}

// ---------------------------------------------------------------------------
extern "C" void kernel_launch(void* const* d_in, const int* in_sizes, int n_in,
                              void* d_out, int out_size, void* d_ws, size_t ws_size,
                              hipStream_t stream) {
    const float* x    = (const float*)d_in[0];
    const float* wf   = (const float*)d_in[1];
    const float* mask = (const float*)d_in[2];
    const float* sW1  = (const float*)d_in[3];
    const float* sW2  = (const float*)d_in[4];
    const float* sW3  = (const float*)d_in[5];
    const float* tW1  = (const float*)d_in[6];
    const float* tW2  = (const float*)d_in[7];
    const float* tW3  = (const float*)d_in[8];
    const float* sb1  = (const float*)d_in[9];
    const float* sb2  = (const float*)d_in[10];
    const float* sb3  = (const float*)d_in[11];
    const float* tb1  = (const float*)d_in[12];
    const float* tb2  = (const float*)d_in[13];
    const float* tb3  = (const float*)d_in[14];
    float* out = (float*)d_out;

    u16* bfrag = (u16*)d_ws;
    // bfrag: 288*16*1024 B = 4,718,592 B (1024-aligned)
    float* precomp = (float*)((char*)d_ws + (size_t)NKS_TOTAL * 16 * 1024);
    // precomp: 2 * 16384 * 256 * 4 B = 33.6 MB  (total ws use ~36.5 MB)

    prep_b<<<dim3(NKS_TOTAL, 4), 256, 0, stream>>>(sW1, tW1, bfrag);
    gemm_big<<<dim3(BATCH / 64, KSPLIT), 256, 0, stream>>>(wf, bfrag, precomp);
    tail_kernel<<<dim3(BATCH / 64), 64, 0, stream>>>(
        x, mask, sW1, sW2, sW3, sb1, sb2, sb3,
        tW1, tW2, tW3, tb1, tb2, tb3, precomp, out);
}